// Round 9
// baseline (1409.208 us; speedup 1.0000x reference)
//
#include <hip/hip_runtime.h>

// Residual VQ on MI355X (gfx950).
// z: [8, 32768, 32] f32; codebooks: [10, 512, 32] f32.
// Outputs (flat f32 in d_out): quantized [B,N,D], indices [B,N,Q] (as float),
// commit_loss [Q] (zeros).
//
// R9 = R8 (4 points/thread, f32x32 SSA state, half-codebook LDS staging,
// no-workspace, replay kernel) minus the cA/cB candidate double-buffer:
// R8 hit the 256-VGPR cap and spilled ~300 MB to scratch (WRITE_SIZE 318 MB
// vs ~11 MB expected) -- the double-buffer's +64 regs pushed demand past the
// file. LDS broadcast latency (~64 cyc) pipelines under the 172 independent
// VALU ops per candidate without it; #pragma unroll 2 lets the scheduler
// keep two candidate ds_read chains in flight. Per-candidate CU balance:
// 256 LDS-cyc vs 352 VALU-cyc -> VALU-bound.
// Distance arithmetic bit-identical to R1 (absmax 0.0 pre+post R7/R8):
// 8-accumulator j&7 dot, dist = fma(-2,dot,rr)+cc, ascending-k strict-<
// first-min. Straight-through chain replayed bit-exactly by the proven
// replay kernel.

#define RVQ_B 8
#define RVQ_N 32768
#define RVQ_D 32
#define RVQ_Q 10
#define RVQ_C 512

static constexpr int  NPTS     = RVQ_B * RVQ_N;             // 262144
static constexpr long IDX_OFF  = (long)NPTS * RVQ_D;        // 8388608
static constexpr long LOSS_OFF = IDX_OFF + (long)NPTS * RVQ_Q;
static constexpr int  HALF     = RVQ_C / 2;                 // 256 codewords

typedef __attribute__((ext_vector_type(32))) float f32x32;

// ---------------------------------------------------------------------------
// helpers (all constant-indexed -> pure SSA)
__device__ __forceinline__ float dot_self(const f32x32& v) {
    float a[8];
#pragma unroll
    for (int j = 0; j < 8; ++j) a[j] = v[j] * v[j];
#pragma unroll
    for (int j = 8; j < RVQ_D; ++j) a[j & 7] = fmaf(v[j], v[j], a[j & 7]);
    return ((a[0] + a[1]) + (a[2] + a[3])) + ((a[4] + a[5]) + (a[6] + a[7]));
}

__device__ __forceinline__ void eval1(const f32x32& r, const f32x32& c,
                                      float rr, float cc, int k,
                                      float& best, int& bidx) {
    float a[8];
#pragma unroll
    for (int j = 0; j < 8; ++j) a[j] = r[j] * c[j];
#pragma unroll
    for (int j = 8; j < RVQ_D; ++j) a[j & 7] = fmaf(r[j], c[j], a[j & 7]);
    const float dot = ((a[0] + a[1]) + (a[2] + a[3])) + ((a[4] + a[5]) + (a[6] + a[7]));
    const float dist = fmaf(-2.0f, dot, rr) + cc;
    if (dist < best) { best = dist; bidx = k; }   // ascending-k strict-< = first-min
}

// bit-exact straight-through residual update: qst = r + (c - r); r' = r - qst
__device__ __forceinline__ f32x32 st_update(const f32x32& r, const f32x32& g) {
    const f32x32 t   = g - r;
    const f32x32 qst = r + t;
    return r - qst;
}

// ---------------------------------------------------------------------------
// Kernel 1: argmin search, 4 points/thread, half-codebook staged in LDS.
__global__ __launch_bounds__(256, 1) void rvq_search(const float* __restrict__ z,
                                                     const float* __restrict__ cb,
                                                     float* __restrict__ out) {
    __shared__ __align__(128) float scb[HALF * RVQ_D];   // 32 KB
    __shared__ float snorm[HALF];                        // 1 KB

    const int  t  = blockIdx.x * 256 + threadIdx.x;   // 65536 threads
    const long p0 = (long)t * 4;

    const f32x32* zv = (const f32x32*)(z + p0 * RVQ_D);
    f32x32 r0 = zv[0], r1 = zv[1], r2 = zv[2], r3 = zv[3];

#pragma unroll 1
    for (int q = 0; q < RVQ_Q; ++q) {
        const f32x32* cv   = (const f32x32*)(cb + (long)q * RVQ_C * RVQ_D);
        const float4* cbq4 = (const float4*)(cb + (long)q * RVQ_C * RVQ_D);

        const float rr0 = dot_self(r0), rr1 = dot_self(r1);
        const float rr2 = dot_self(r2), rr3 = dot_self(r3);

        float best0 = __builtin_inff(), best1 = __builtin_inff();
        float best2 = __builtin_inff(), best3 = __builtin_inff();
        int b0 = 0, b1 = 0, b2 = 0, b3 = 0;

#pragma unroll 1
        for (int h = 0; h < 2; ++h) {
            __syncthreads();   // prior half/stage reads complete before overwrite
            // ---- stage 256 codewords -> LDS (coalesced float4, stride-1 writes)
#pragma unroll
            for (int i = 0; i < 8; ++i) {
                const int idx = threadIdx.x + 256 * i;   // 2048 float4 = 32 KB
                ((float4*)scb)[idx] = cbq4[h * (HALF * 8) + idx];
            }
            // ---- norms (bit-exact numpy tree, pure function of cb)
            snorm[threadIdx.x] = dot_self(cv[h * HALF + threadIdx.x]);
            __syncthreads();

            const f32x32* sv = (const f32x32*)scb;
            const int kg0 = h * HALF;

#pragma unroll 2
            for (int k = 0; k < HALF; ++k) {
                const f32x32 c  = sv[k];        // broadcast ds_read_b128 x8
                const float  cc = snorm[k];
                eval1(r0, c, rr0, cc, kg0 + k, best0, b0);
                eval1(r1, c, rr1, cc, kg0 + k, best1, b1);
                eval1(r2, c, rr2, cc, kg0 + k, best2, b2);
                eval1(r3, c, rr3, cc, kg0 + k, best3, b3);
            }
        }

        // indices (as float, layout [B,N,Q])
        out[IDX_OFF + (p0 + 0) * RVQ_Q + q] = (float)b0;
        out[IDX_OFF + (p0 + 1) * RVQ_Q + q] = (float)b1;
        out[IDX_OFF + (p0 + 2) * RVQ_Q + q] = (float)b2;
        out[IDX_OFF + (p0 + 3) * RVQ_Q + q] = (float)b3;

        // gather chosen codewords from global (R7-proven), update residuals
        const f32x32 g0 = cv[b0];
        const f32x32 g1 = cv[b1];
        const f32x32 g2 = cv[b2];
        const f32x32 g3 = cv[b3];

        r0 = st_update(r0, g0);
        r1 = st_update(r1, g1);
        r2 = st_update(r2, g2);
        r3 = st_update(r3, g3);
    }
}

// ---------------------------------------------------------------------------
// Kernel 2: replay the straight-through chain from stored indices; writes
// quantized + commit_loss. Bit-identical op order to the reference.
// (Proven pre+post-timing in R3/R4/R5/R7/R8.)
__global__ __launch_bounds__(256) void rvq_replay(const float* __restrict__ z,
                                                  const float* __restrict__ cb,
                                                  float* __restrict__ out) {
    const int p = blockIdx.x * 256 + threadIdx.x;

    float r[RVQ_D], oacc[RVQ_D];
    {
        const float4* zp = (const float4*)(z + (long)p * RVQ_D);
#pragma unroll
        for (int w = 0; w < 8; ++w) {
            const float4 v = zp[w];
            r[w * 4 + 0] = v.x; r[w * 4 + 1] = v.y;
            r[w * 4 + 2] = v.z; r[w * 4 + 3] = v.w;
        }
    }
#pragma unroll
    for (int d = 0; d < RVQ_D; ++d) oacc[d] = 0.0f;

#pragma unroll 1
    for (int q = 0; q < RVQ_Q; ++q) {
        const int idx = (int)out[IDX_OFF + (long)p * RVQ_Q + q];
        const float4* cwb = (const float4*)(cb + ((long)q * RVQ_C + idx) * RVQ_D);
        float cwv[RVQ_D];
#pragma unroll
        for (int w = 0; w < 8; ++w) {
            const float4 v = cwb[w];
            cwv[w * 4 + 0] = v.x; cwv[w * 4 + 1] = v.y;
            cwv[w * 4 + 2] = v.z; cwv[w * 4 + 3] = v.w;
        }
#pragma unroll
        for (int d = 0; d < RVQ_D; ++d) {
            const float qst = r[d] + (cwv[d] - r[d]);
            oacc[d] += qst;
            r[d] = r[d] - qst;
        }
    }

    float4* qo = (float4*)(out + (long)p * RVQ_D);
#pragma unroll
    for (int w = 0; w < 8; ++w) {
        float4 v;
        v.x = oacc[w * 4 + 0]; v.y = oacc[w * 4 + 1];
        v.z = oacc[w * 4 + 2]; v.w = oacc[w * 4 + 3];
        qo[w] = v;
    }

    if (p < RVQ_Q) out[LOSS_OFF + p] = 0.0f;
}

// ---------------------------------------------------------------------------
extern "C" void kernel_launch(void* const* d_in, const int* in_sizes, int n_in,
                              void* d_out, int out_size, void* d_ws, size_t ws_size,
                              hipStream_t stream) {
    const float* z  = (const float*)d_in[0];
    const float* cb = (const float*)d_in[1];
    float* out = (float*)d_out;
    (void)d_ws; (void)ws_size;  // no workspace (R6 post-timing lesson)

    rvq_search<<<NPTS / 4 / 256, 256, 0, stream>>>(z, cb, out);
    rvq_replay<<<NPTS / 256, 256, 0, stream>>>(z, cb, out);
}